// Round 5
// baseline (204.950 us; speedup 1.0000x reference)
//
#include <hip/hip_runtime.h>

namespace {

constexpr int NROWS = 8192;  // N
constexpr int C = 1600;      // classes
constexpr int C4 = C / 4;    // 400
constexpr int L = 4;         // hierarchy levels
constexpr int K = 256;       // labels per level

constexpr int TB = 320;               // 5 waves; 1600 float4 / 320 = 5/thread
constexpr int BOX_BLOCKS = NROWS;     // one box row per block (25.6 KB)
constexpr int CLS_BLOCKS = NROWS / 4; // one 4-row cls group per block

// Packed extras chain for column j: out[j] = (deepest-first extras) + in[j]
// x = n | idx0<<4 | idx1<<15 ; y = idx2 | idx3<<11   (indices < 2048)

// ---------------------------------------------------------------------------
// Build per-column extras chains (verified walk, unchanged from R3/R4).
// cls : level i writes tgt_i[k] = old[src_i[k]] + orig[tgt_i[k]]
// box : level i writes src_i[k] = old[tgt_i[k]] + orig[src_i[k]]
// ---------------------------------------------------------------------------
__global__ __launch_bounds__(1024) void build_chains(
    const int* __restrict__ tgt, const int* __restrict__ src,
    uint2* __restrict__ pc_cls, uint2* __restrict__ pc_box) {
  __shared__ short tpos[L][C];
  __shared__ short spos[L][C];
  __shared__ short tg[L][K];
  __shared__ short sr[L][K];
  const int tid = threadIdx.x, nt = blockDim.x;

  for (int i = tid; i < L * C; i += nt) {
    (&tpos[0][0])[i] = -1;
    (&spos[0][0])[i] = -1;
  }
  __syncthreads();
  for (int i = tid; i < L * K; i += nt) {
    const int lvl = i / K, k = i % K;
    const int t = tgt[i], s = src[i];
    (&tg[0][0])[i] = (short)t;
    (&sr[0][0])[i] = (short)s;
    tpos[lvl][t] = (short)k;  // unique within a level (permutation slice)
    spos[lvl][s] = (short)k;
  }
  __syncthreads();

  for (int j = tid; j < C; j += nt) {
    {  // ---- cls ----
      int idx[4] = {0, 0, 0, 0};
      int cnt = 0, x = j, lvl = L - 1;
      for (;;) {
        int fi = -1, fk = -1;
        for (int i = lvl; i >= 0; --i) {
          const short p = tpos[i][x];
          if (p >= 0) { fi = i; fk = p; break; }
        }
        if (fi < 0) break;
        x = sr[fi][fk];
        lvl = fi - 1;
        idx[cnt++] = x;
      }
      uint2 p;
      p.x = (unsigned)cnt | ((unsigned)idx[0] << 4) | ((unsigned)idx[1] << 15);
      p.y = (unsigned)idx[2] | ((unsigned)idx[3] << 11);
      pc_cls[j] = p;
    }
    {  // ---- box (src/tgt swapped) ----
      int idx[4] = {0, 0, 0, 0};
      int cnt = 0, x = j, lvl = L - 1;
      for (;;) {
        int fi = -1, fk = -1;
        for (int i = lvl; i >= 0; --i) {
          const short p = spos[i][x];
          if (p >= 0) { fi = i; fk = p; break; }
        }
        if (fi < 0) break;
        x = tg[fi][fk];
        lvl = fi - 1;
        idx[cnt++] = x;
      }
      uint2 p;
      p.x = (unsigned)cnt | ((unsigned)idx[0] << 4) | ((unsigned)idx[1] << 15);
      p.y = (unsigned)idx[2] | ((unsigned)idx[3] << 11);
      pc_box[j] = p;
    }
  }
}

__device__ __forceinline__ void add4(float4& s, const float4 a) {
  s.x += a.x; s.y += a.y; s.z += a.z; s.w += a.w;
}

// ---------------------------------------------------------------------------
// Fused apply, pure streaming — no LDS, no barriers. Each block owns the
// exact window its gathers read (one 25.6 KB box row / one 4-row cls group),
// so stream + gather requests come from one CU -> one L1 / one XCD-L2;
// L2 MSHRs dedup and gathers are cache hits. Extras accumulate deepest-first,
// base last == reference association order (bit-exact, absmax 0 in R4).
// ---------------------------------------------------------------------------
__global__ __launch_bounds__(TB) void apply_fused(
    const float* __restrict__ logits, const float4* __restrict__ box,
    const uint2* __restrict__ pc_cls, const uint2* __restrict__ pc_box,
    float* __restrict__ out_cls, float4* __restrict__ out_box) {
  const int tid = threadIdx.x;

  if (blockIdx.x < (unsigned)BOX_BLOCKS) {
    // ---------------- box: one row ----------------
    const float4* row = box + (size_t)blockIdx.x * C;
    float4* orow = out_box + (size_t)blockIdx.x * C;
#pragma unroll
    for (int k = 0; k < 5; ++k) {
      const int col = tid + k * TB;
      const uint2 p = pc_box[col];
      const float4 b = row[col];
      const int n = p.x & 0xF;
      float4 a = make_float4(0.f, 0.f, 0.f, 0.f);
      if (n > 3) add4(a, row[(p.y >> 11) & 0x7FF]);
      if (n > 2) add4(a, row[p.y & 0x7FF]);
      if (n > 1) add4(a, row[(p.x >> 15) & 0x7FF]);
      if (n > 0) add4(a, row[(p.x >> 4) & 0x7FF]);
      add4(a, b);  // base last = reference order
      orow[col] = a;
    }
  } else {
    // ---------------- cls: one 4-row group ----------------
    const int g = blockIdx.x - BOX_BLOCKS;
    const float* rows = logits + (size_t)g * (4 * C);
    float4* o4 = (float4*)out_cls + (size_t)g * C;  // 1600 float4 per group
    const uint4* pc4 = (const uint4*)pc_cls;        // 2 uint4 = 4 chains
#pragma unroll
    for (int k = 0; k < 5; ++k) {
      const int s = tid + k * TB;  // slot in group: r*400 + c4
      const int r = s / 400;
      const int c4 = s - r * 400;
      const float* rw = rows + r * C;
      float4 v = ((const float4*)rw)[c4];
      const uint4 pA = pc4[2 * c4];      // chains for cols 4c4, 4c4+1
      const uint4 pB = pc4[2 * c4 + 1];  // chains for cols 4c4+2, 4c4+3
      float acc;
      {
        const int n = pA.x & 0xF; acc = 0.f;
        if (n > 3) acc += rw[(pA.y >> 11) & 0x7FF];
        if (n > 2) acc += rw[pA.y & 0x7FF];
        if (n > 1) acc += rw[(pA.x >> 15) & 0x7FF];
        if (n > 0) acc += rw[(pA.x >> 4) & 0x7FF];
        v.x = acc + v.x;
      }
      {
        const int n = pA.z & 0xF; acc = 0.f;
        if (n > 3) acc += rw[(pA.w >> 11) & 0x7FF];
        if (n > 2) acc += rw[pA.w & 0x7FF];
        if (n > 1) acc += rw[(pA.z >> 15) & 0x7FF];
        if (n > 0) acc += rw[(pA.z >> 4) & 0x7FF];
        v.y = acc + v.y;
      }
      {
        const int n = pB.x & 0xF; acc = 0.f;
        if (n > 3) acc += rw[(pB.y >> 11) & 0x7FF];
        if (n > 2) acc += rw[pB.y & 0x7FF];
        if (n > 1) acc += rw[(pB.x >> 15) & 0x7FF];
        if (n > 0) acc += rw[(pB.x >> 4) & 0x7FF];
        v.z = acc + v.z;
      }
      {
        const int n = pB.z & 0xF; acc = 0.f;
        if (n > 3) acc += rw[(pB.w >> 11) & 0x7FF];
        if (n > 2) acc += rw[pB.w & 0x7FF];
        if (n > 1) acc += rw[(pB.z >> 15) & 0x7FF];
        if (n > 0) acc += rw[(pB.z >> 4) & 0x7FF];
        v.w = acc + v.w;
      }
      o4[s] = v;
    }
  }
}

}  // namespace

extern "C" void kernel_launch(void* const* d_in, const int* in_sizes, int n_in,
                              void* d_out, int out_size, void* d_ws, size_t ws_size,
                              hipStream_t stream) {
  const float* logits = (const float*)d_in[0];  // (N, C)
  const float* boxr   = (const float*)d_in[1];  // (N, 4C) == (N, C) float4
  const int*   tgt    = (const int*)d_in[2];    // (L, K)
  const int*   src    = (const int*)d_in[3];    // (L, K)

  float* out_cls = (float*)d_out;                // (N, C)
  float* out_box = out_cls + (size_t)NROWS * C;  // (N, 4C)

  uint2* pc_cls = (uint2*)d_ws;  // 12.8 KB
  uint2* pc_box = pc_cls + C;    // 12.8 KB

  build_chains<<<1, 1024, 0, stream>>>(tgt, src, pc_cls, pc_box);
  apply_fused<<<BOX_BLOCKS + CLS_BLOCKS, TB, 0, stream>>>(
      logits, (const float4*)boxr, pc_cls, pc_box, out_cls, (float4*)out_box);
}

// Round 6
// 130.990 us; speedup vs baseline: 1.5646x; 1.5646x over previous
//
#include <hip/hip_runtime.h>

namespace {

constexpr int NROWS = 8192;  // N
constexpr int C = 1600;      // classes
constexpr int L = 4;         // hierarchy levels
constexpr int K = 256;       // labels per level

constexpr int TB = 320;          // 5 waves; 1600 float4 / 320 = 5 per thread
constexpr int CPB = 8;           // chunks per block
constexpr int BOX_BLOCKS = 1024; // 8192 rows / 8
constexpr int CLS_BLOCKS = 256;  // 2048 groups / 8

// Packed extras chain for column j: out[j] = (deepest-first extras) + in[j]
// x = n | idx0<<4 | idx1<<15 ; y = idx2 | idx3<<11   (indices < 2048)

// ---------------------------------------------------------------------------
// Build per-column extras chains (verified walk, unchanged since R3).
// cls : level i writes tgt_i[k] = old[src_i[k]] + orig[tgt_i[k]]
// box : level i writes src_i[k] = old[tgt_i[k]] + orig[src_i[k]]
// ---------------------------------------------------------------------------
__global__ __launch_bounds__(1024) void build_chains(
    const int* __restrict__ tgt, const int* __restrict__ src,
    uint2* __restrict__ pc_cls, uint2* __restrict__ pc_box) {
  __shared__ short tpos[L][C];
  __shared__ short spos[L][C];
  __shared__ short tg[L][K];
  __shared__ short sr[L][K];
  const int tid = threadIdx.x, nt = blockDim.x;

  for (int i = tid; i < L * C; i += nt) {
    (&tpos[0][0])[i] = -1;
    (&spos[0][0])[i] = -1;
  }
  __syncthreads();
  for (int i = tid; i < L * K; i += nt) {
    const int lvl = i / K, k = i % K;
    const int t = tgt[i], s = src[i];
    (&tg[0][0])[i] = (short)t;
    (&sr[0][0])[i] = (short)s;
    tpos[lvl][t] = (short)k;  // unique within a level (permutation slice)
    spos[lvl][s] = (short)k;
  }
  __syncthreads();

  for (int j = tid; j < C; j += nt) {
    {  // ---- cls ----
      int idx[4] = {0, 0, 0, 0};
      int cnt = 0, x = j, lvl = L - 1;
      for (;;) {
        int fi = -1, fk = -1;
        for (int i = lvl; i >= 0; --i) {
          const short p = tpos[i][x];
          if (p >= 0) { fi = i; fk = p; break; }
        }
        if (fi < 0) break;
        x = sr[fi][fk];
        lvl = fi - 1;
        idx[cnt++] = x;
      }
      uint2 p;
      p.x = (unsigned)cnt | ((unsigned)idx[0] << 4) | ((unsigned)idx[1] << 15);
      p.y = (unsigned)idx[2] | ((unsigned)idx[3] << 11);
      pc_cls[j] = p;
    }
    {  // ---- box (src/tgt swapped) ----
      int idx[4] = {0, 0, 0, 0};
      int cnt = 0, x = j, lvl = L - 1;
      for (;;) {
        int fi = -1, fk = -1;
        for (int i = lvl; i >= 0; --i) {
          const short p = spos[i][x];
          if (p >= 0) { fi = i; fk = p; break; }
        }
        if (fi < 0) break;
        x = tg[fi][fk];
        lvl = fi - 1;
        idx[cnt++] = x;
      }
      uint2 p;
      p.x = (unsigned)cnt | ((unsigned)idx[0] << 4) | ((unsigned)idx[1] << 15);
      p.y = (unsigned)idx[2] | ((unsigned)idx[3] << 11);
      pc_box[j] = p;
    }
  }
}

__device__ __forceinline__ void gload16(const void* g, void* l) {
  __builtin_amdgcn_global_load_lds(
      (const __attribute__((address_space(1))) unsigned int*)g,
      (__attribute__((address_space(3))) unsigned int*)l, 16, 0, 0);
}

__device__ __forceinline__ void add4(float4& s, const float4 a) {
  s.x += a.x; s.y += a.y; s.z += a.z; s.w += a.w;
}

// ---------------------------------------------------------------------------
// Fused apply. Double-buffered 25.6 KB chunks staged with async
// global_load_lds. T4 discipline: per chunk each thread issues 5 stage loads
// then 5 output stores; s_waitcnt vmcnt(5) at the chunk boundary completes
// the prefetch loads while the 5 newest VMEM ops (this chunk's stores) stay
// in flight -> store acks and load latency leave the critical path.
//   blocks [0, BOX_BLOCKS)  : chunk = 1 box row   (1600 float4)
//   blocks [BOX_BLOCKS, ..) : chunk = 4 cls rows  (1600 float4)
// Extras deepest-first, base last == reference association order (bit-exact).
// ---------------------------------------------------------------------------
__global__ __launch_bounds__(TB) void apply_fused(
    const float* __restrict__ logits, const float4* __restrict__ box,
    const uint2* __restrict__ pc_cls, const uint2* __restrict__ pc_box,
    float* __restrict__ out_cls, float4* __restrict__ out_box) {
  __shared__ float4 smem[2][C];  // 51.2 KB
  const int tid = threadIdx.x;
  const int wave = tid >> 6, lane = tid & 63;

  // stage one 25.6 KB contiguous chunk: 5 gload16 per thread, uniform
  auto stage = [&](int buf, const void* src) {
#pragma unroll
    for (int k = 0; k < 5; ++k) {
      const int u = k * 5 + wave;  // 25 1KB-units
      gload16((const char*)src + u * 1024 + lane * 16,
              (char*)&smem[buf][0] + u * 1024);
    }
    __builtin_amdgcn_sched_barrier(0);  // pin load-issue before the stores
  };

  if (blockIdx.x < (unsigned)BOX_BLOCKS) {
    // ---------------- box: one row per chunk ----------------
    const int r0 = blockIdx.x * CPB;
    uint2 ch[5];
    stage(0, box + (size_t)r0 * C);
#pragma unroll
    for (int k = 0; k < 5; ++k) ch[k] = pc_box[tid + k * TB];
    asm volatile("s_waitcnt vmcnt(0)" ::: "memory");
    __builtin_amdgcn_s_barrier();
    int cur = 0;
#pragma unroll 1
    for (int c = 0; c < CPB; ++c) {
      if (c + 1 < CPB) stage(cur ^ 1, box + (size_t)(r0 + c + 1) * C);
      const float4* row = smem[cur];
      float4* orow = out_box + (size_t)(r0 + c) * C;
#pragma unroll
      for (int k = 0; k < 5; ++k) {
        const int col = tid + k * TB;
        const uint2 p = ch[k];
        const int n = p.x & 0xF;
        float4 a = make_float4(0.f, 0.f, 0.f, 0.f);
        if (n > 3) add4(a, row[(p.y >> 11) & 0x7FF]);
        if (n > 2) add4(a, row[p.y & 0x7FF]);
        if (n > 1) add4(a, row[(p.x >> 15) & 0x7FF]);
        if (n > 0) add4(a, row[(p.x >> 4) & 0x7FF]);
        add4(a, row[col]);  // base last = reference order
        orow[col] = a;
      }
      if (c + 1 < CPB) {
        asm volatile("s_waitcnt vmcnt(5)" ::: "memory");
        __builtin_amdgcn_sched_barrier(0);
        __builtin_amdgcn_s_barrier();
        __builtin_amdgcn_sched_barrier(0);
      }
      cur ^= 1;
    }
  } else {
    // ---------------- cls: four rows per chunk ----------------
    const int g0 = (blockIdx.x - BOX_BLOCKS) * CPB;
    uint2 ch[5][4];
    stage(0, logits + (size_t)g0 * (4 * C));
#pragma unroll
    for (int k = 0; k < 5; ++k) {
      const int c4 = (tid + k * TB) % 400;
#pragma unroll
      for (int e = 0; e < 4; ++e) ch[k][e] = pc_cls[c4 * 4 + e];
    }
    asm volatile("s_waitcnt vmcnt(0)" ::: "memory");
    __builtin_amdgcn_s_barrier();
    int cur = 0;
#pragma unroll 1
    for (int c = 0; c < CPB; ++c) {
      if (c + 1 < CPB) stage(cur ^ 1, logits + (size_t)(g0 + c + 1) * (4 * C));
      const float* rows = (const float*)smem[cur];           // [4][1600]
      float4* o4 = (float4*)out_cls + (size_t)(g0 + c) * C;  // [4][400] f4
#pragma unroll
      for (int k = 0; k < 5; ++k) {
        const int s4 = tid + k * TB;  // slot in chunk, r*400+c4
        const int r = s4 / 400;
        const int c4 = s4 - r * 400;
        const float* rw = rows + r * C;
        float4 v = ((const float4*)rw)[c4];
        float acc;
        {
          const uint2 p = ch[k][0]; const int n = p.x & 0xF; acc = 0.f;
          if (n > 3) acc += rw[(p.y >> 11) & 0x7FF];
          if (n > 2) acc += rw[p.y & 0x7FF];
          if (n > 1) acc += rw[(p.x >> 15) & 0x7FF];
          if (n > 0) acc += rw[(p.x >> 4) & 0x7FF];
          v.x = acc + v.x;
        }
        {
          const uint2 p = ch[k][1]; const int n = p.x & 0xF; acc = 0.f;
          if (n > 3) acc += rw[(p.y >> 11) & 0x7FF];
          if (n > 2) acc += rw[p.y & 0x7FF];
          if (n > 1) acc += rw[(p.x >> 15) & 0x7FF];
          if (n > 0) acc += rw[(p.x >> 4) & 0x7FF];
          v.y = acc + v.y;
        }
        {
          const uint2 p = ch[k][2]; const int n = p.x & 0xF; acc = 0.f;
          if (n > 3) acc += rw[(p.y >> 11) & 0x7FF];
          if (n > 2) acc += rw[p.y & 0x7FF];
          if (n > 1) acc += rw[(p.x >> 15) & 0x7FF];
          if (n > 0) acc += rw[(p.x >> 4) & 0x7FF];
          v.z = acc + v.z;
        }
        {
          const uint2 p = ch[k][3]; const int n = p.x & 0xF; acc = 0.f;
          if (n > 3) acc += rw[(p.y >> 11) & 0x7FF];
          if (n > 2) acc += rw[p.y & 0x7FF];
          if (n > 1) acc += rw[(p.x >> 15) & 0x7FF];
          if (n > 0) acc += rw[(p.x >> 4) & 0x7FF];
          v.w = acc + v.w;
        }
        o4[s4] = v;
      }
      if (c + 1 < CPB) {
        asm volatile("s_waitcnt vmcnt(5)" ::: "memory");
        __builtin_amdgcn_sched_barrier(0);
        __builtin_amdgcn_s_barrier();
        __builtin_amdgcn_sched_barrier(0);
      }
      cur ^= 1;
    }
  }
}

}  // namespace

extern "C" void kernel_launch(void* const* d_in, const int* in_sizes, int n_in,
                              void* d_out, int out_size, void* d_ws, size_t ws_size,
                              hipStream_t stream) {
  const float* logits = (const float*)d_in[0];  // (N, C)
  const float* boxr   = (const float*)d_in[1];  // (N, 4C) == (N, C) float4
  const int*   tgt    = (const int*)d_in[2];    // (L, K)
  const int*   src    = (const int*)d_in[3];    // (L, K)

  float* out_cls = (float*)d_out;                // (N, C)
  float* out_box = out_cls + (size_t)NROWS * C;  // (N, 4C)

  uint2* pc_cls = (uint2*)d_ws;  // 12.8 KB
  uint2* pc_box = pc_cls + C;    // 12.8 KB

  build_chains<<<1, 1024, 0, stream>>>(tgt, src, pc_cls, pc_box);
  apply_fused<<<BOX_BLOCKS + CLS_BLOCKS, TB, 0, stream>>>(
      logits, (const float4*)boxr, pc_cls, pc_box, out_cls, (float4*)out_box);
}

// Round 7
// 108.226 us; speedup vs baseline: 1.8937x; 1.2103x over previous
//
#include <hip/hip_runtime.h>

namespace {

constexpr int NROWS = 8192;  // N
constexpr int C = 1600;      // classes
constexpr int L = 4;         // hierarchy levels
constexpr int K = 256;       // labels per level

constexpr int TB = 320;                 // 5 waves; 1600 f4 / 320 = 5/thread
constexpr int BOX_BLOCKS = NROWS;       // one box row per block (25.6 KB)
constexpr int CLS_BLOCKS = NROWS / 4;   // one 4-row cls group per block

// Packed extras chain for column j: out[j] = (deepest-first extras) + in[j]
// x = n | idx0<<4 | idx1<<15 ; y = idx2 | idx3<<11   (indices < 2048)

// ---------------------------------------------------------------------------
// Build per-column extras chains (verified walk, unchanged since R3).
// cls : level i writes tgt_i[k] = old[src_i[k]] + orig[tgt_i[k]]
// box : level i writes src_i[k] = old[tgt_i[k]] + orig[src_i[k]]
// ---------------------------------------------------------------------------
__global__ __launch_bounds__(1024) void build_chains(
    const int* __restrict__ tgt, const int* __restrict__ src,
    uint2* __restrict__ pc_cls, uint2* __restrict__ pc_box) {
  __shared__ short tpos[L][C];
  __shared__ short spos[L][C];
  __shared__ short tg[L][K];
  __shared__ short sr[L][K];
  const int tid = threadIdx.x, nt = blockDim.x;

  for (int i = tid; i < L * C; i += nt) {
    (&tpos[0][0])[i] = -1;
    (&spos[0][0])[i] = -1;
  }
  __syncthreads();
  for (int i = tid; i < L * K; i += nt) {
    const int lvl = i / K, k = i % K;
    const int t = tgt[i], s = src[i];
    (&tg[0][0])[i] = (short)t;
    (&sr[0][0])[i] = (short)s;
    tpos[lvl][t] = (short)k;  // unique within a level (permutation slice)
    spos[lvl][s] = (short)k;
  }
  __syncthreads();

  for (int j = tid; j < C; j += nt) {
    {  // ---- cls ----
      int idx[4] = {0, 0, 0, 0};
      int cnt = 0, x = j, lvl = L - 1;
      for (;;) {
        int fi = -1, fk = -1;
        for (int i = lvl; i >= 0; --i) {
          const short p = tpos[i][x];
          if (p >= 0) { fi = i; fk = p; break; }
        }
        if (fi < 0) break;
        x = sr[fi][fk];
        lvl = fi - 1;
        idx[cnt++] = x;
      }
      uint2 p;
      p.x = (unsigned)cnt | ((unsigned)idx[0] << 4) | ((unsigned)idx[1] << 15);
      p.y = (unsigned)idx[2] | ((unsigned)idx[3] << 11);
      pc_cls[j] = p;
    }
    {  // ---- box (src/tgt swapped) ----
      int idx[4] = {0, 0, 0, 0};
      int cnt = 0, x = j, lvl = L - 1;
      for (;;) {
        int fi = -1, fk = -1;
        for (int i = lvl; i >= 0; --i) {
          const short p = spos[i][x];
          if (p >= 0) { fi = i; fk = p; break; }
        }
        if (fi < 0) break;
        x = tg[fi][fk];
        lvl = fi - 1;
        idx[cnt++] = x;
      }
      uint2 p;
      p.x = (unsigned)cnt | ((unsigned)idx[0] << 4) | ((unsigned)idx[1] << 15);
      p.y = (unsigned)idx[2] | ((unsigned)idx[3] << 11);
      pc_box[j] = p;
    }
  }
}

__device__ __forceinline__ void gload16(const void* g, void* l) {
  __builtin_amdgcn_global_load_lds(
      (const __attribute__((address_space(1))) unsigned int*)g,
      (__attribute__((address_space(3))) unsigned int*)l, 16, 0, 0);
}

__device__ __forceinline__ void add4(float4& s, const float4 a) {
  s.x += a.x; s.y += a.y; s.z += a.z; s.w += a.w;
}

// ---------------------------------------------------------------------------
// Fused apply — one-shot blocks, max TLP. One 25.6 KB chunk per block staged
// async to a single LDS buffer; chains load during the gload flight; ONE
// barrier; gather/add/store; exit. 25.6 KB LDS + low VGPR -> 6 blocks/CU
// (30 waves/CU): six staggered blocks per CU keep HBM loads, LDS reads and
// stores concurrently in flight with no serial chunk chain.
//   blocks [0, BOX_BLOCKS)  : 1 box row   (1600 float4)
//   blocks [BOX_BLOCKS, ..) : 4 cls rows  (1600 float4)
// Extras deepest-first, base last == reference association order (bit-exact).
// ---------------------------------------------------------------------------
__global__ __launch_bounds__(TB) void apply_fused(
    const float* __restrict__ logits, const float4* __restrict__ box,
    const uint2* __restrict__ pc_cls, const uint2* __restrict__ pc_box,
    float* __restrict__ out_cls, float4* __restrict__ out_box) {
  __shared__ float4 smem[C];  // 25.6 KB
  const int tid = threadIdx.x;
  const int wave = tid >> 6, lane = tid & 63;

  const bool is_box = blockIdx.x < (unsigned)BOX_BLOCKS;
  const void* src = is_box
      ? (const void*)(box + (size_t)blockIdx.x * C)
      : (const void*)(logits + (size_t)(blockIdx.x - BOX_BLOCKS) * (4 * C));

  // stage the 25.6 KB chunk: 5 gload16 per thread (25 x 1 KB units)
#pragma unroll
  for (int k = 0; k < 5; ++k) {
    const int u = k * 5 + wave;
    gload16((const char*)src + u * 1024 + lane * 16,
            (char*)&smem[0] + u * 1024);
  }

  if (is_box) {
    // chain loads overlap the gload flight (12.8 KB table, L2-hot)
    uint2 ch[5];
#pragma unroll
    for (int k = 0; k < 5; ++k) ch[k] = pc_box[tid + k * TB];
    asm volatile("s_waitcnt vmcnt(0)" ::: "memory");
    __syncthreads();

    const float4* row = smem;
    float4* orow = out_box + (size_t)blockIdx.x * C;
#pragma unroll
    for (int k = 0; k < 5; ++k) {
      const int col = tid + k * TB;
      const uint2 p = ch[k];
      const int n = p.x & 0xF;
      float4 a = make_float4(0.f, 0.f, 0.f, 0.f);
      if (n > 3) add4(a, row[(p.y >> 11) & 0x7FF]);
      if (n > 2) add4(a, row[p.y & 0x7FF]);
      if (n > 1) add4(a, row[(p.x >> 15) & 0x7FF]);
      if (n > 0) add4(a, row[(p.x >> 4) & 0x7FF]);
      add4(a, row[col]);  // base last = reference order
      orow[col] = a;
    }
  } else {
    const int g = blockIdx.x - BOX_BLOCKS;
    const uint4* pc4 = (const uint4*)pc_cls;  // 2 uint4 = 4 chains
    uint4 chA[5], chB[5];
#pragma unroll
    for (int k = 0; k < 5; ++k) {
      const int s4 = tid + k * TB;
      const int c4 = s4 % 400;
      chA[k] = pc4[2 * c4];
      chB[k] = pc4[2 * c4 + 1];
    }
    asm volatile("s_waitcnt vmcnt(0)" ::: "memory");
    __syncthreads();

    const float* rows = (const float*)smem;        // [4][1600]
    float4* o4 = (float4*)out_cls + (size_t)g * C; // [4][400] float4
#pragma unroll
    for (int k = 0; k < 5; ++k) {
      const int s4 = tid + k * TB;  // r*400 + c4
      const int r = s4 / 400;
      const int c4 = s4 - r * 400;
      const float* rw = rows + r * C;
      float4 v = ((const float4*)rw)[c4];
      const uint4 pA = chA[k], pB = chB[k];
      float acc;
      {
        const int n = pA.x & 0xF; acc = 0.f;
        if (n > 3) acc += rw[(pA.y >> 11) & 0x7FF];
        if (n > 2) acc += rw[pA.y & 0x7FF];
        if (n > 1) acc += rw[(pA.x >> 15) & 0x7FF];
        if (n > 0) acc += rw[(pA.x >> 4) & 0x7FF];
        v.x = acc + v.x;
      }
      {
        const int n = pA.z & 0xF; acc = 0.f;
        if (n > 3) acc += rw[(pA.w >> 11) & 0x7FF];
        if (n > 2) acc += rw[pA.w & 0x7FF];
        if (n > 1) acc += rw[(pA.z >> 15) & 0x7FF];
        if (n > 0) acc += rw[(pA.z >> 4) & 0x7FF];
        v.y = acc + v.y;
      }
      {
        const int n = pB.x & 0xF; acc = 0.f;
        if (n > 3) acc += rw[(pB.y >> 11) & 0x7FF];
        if (n > 2) acc += rw[pB.y & 0x7FF];
        if (n > 1) acc += rw[(pB.x >> 15) & 0x7FF];
        if (n > 0) acc += rw[(pB.x >> 4) & 0x7FF];
        v.z = acc + v.z;
      }
      {
        const int n = pB.z & 0xF; acc = 0.f;
        if (n > 3) acc += rw[(pB.w >> 11) & 0x7FF];
        if (n > 2) acc += rw[pB.w & 0x7FF];
        if (n > 1) acc += rw[(pB.z >> 15) & 0x7FF];
        if (n > 0) acc += rw[(pB.z >> 4) & 0x7FF];
        v.w = acc + v.w;
      }
      o4[s4] = v;
    }
  }
}

}  // namespace

extern "C" void kernel_launch(void* const* d_in, const int* in_sizes, int n_in,
                              void* d_out, int out_size, void* d_ws, size_t ws_size,
                              hipStream_t stream) {
  const float* logits = (const float*)d_in[0];  // (N, C)
  const float* boxr   = (const float*)d_in[1];  // (N, 4C) == (N, C) float4
  const int*   tgt    = (const int*)d_in[2];    // (L, K)
  const int*   src    = (const int*)d_in[3];    // (L, K)

  float* out_cls = (float*)d_out;                // (N, C)
  float* out_box = out_cls + (size_t)NROWS * C;  // (N, 4C)

  uint2* pc_cls = (uint2*)d_ws;  // 12.8 KB
  uint2* pc_box = pc_cls + C;    // 12.8 KB

  build_chains<<<1, 1024, 0, stream>>>(tgt, src, pc_cls, pc_box);
  apply_fused<<<BOX_BLOCKS + CLS_BLOCKS, TB, 0, stream>>>(
      logits, (const float4*)boxr, pc_cls, pc_box, out_cls, (float4*)out_box);
}

// Round 9
// 91.415 us; speedup vs baseline: 2.2420x; 1.1839x over previous
//
#include <hip/hip_runtime.h>

namespace {

constexpr int NROWS = 8192;  // N
constexpr int C = 1600;      // classes
constexpr int L = 4;         // hierarchy levels
constexpr int K = 256;       // labels per level

constexpr int TB = 320;                 // 5 waves; 1600 f4 / 320 = 5/thread
constexpr int BOX_BLOCKS = NROWS;       // one box row per block (25.6 KB)
constexpr int CLS_BLOCKS = NROWS / 4;   // one 4-row cls group per block

// Packed extras chain for column j: out[j] = (deepest-first extras) + in[j]
// x = n | idx0<<4 | idx1<<15 ; y = idx2 | idx3<<11   (indices < 2048)

// ---------------------------------------------------------------------------
// Build per-column extras chains (verified walk, unchanged since R3).
// cls : level i writes tgt_i[k] = old[src_i[k]] + orig[tgt_i[k]]
// box : level i writes src_i[k] = old[tgt_i[k]] + orig[src_i[k]]
// ---------------------------------------------------------------------------
__global__ __launch_bounds__(1024) void build_chains(
    const int* __restrict__ tgt, const int* __restrict__ src,
    uint2* __restrict__ pc_cls, uint2* __restrict__ pc_box) {
  __shared__ short tpos[L][C];
  __shared__ short spos[L][C];
  __shared__ short tg[L][K];
  __shared__ short sr[L][K];
  const int tid = threadIdx.x, nt = blockDim.x;

  for (int i = tid; i < L * C; i += nt) {
    (&tpos[0][0])[i] = -1;
    (&spos[0][0])[i] = -1;
  }
  __syncthreads();
  for (int i = tid; i < L * K; i += nt) {
    const int lvl = i / K, k = i % K;
    const int t = tgt[i], s = src[i];
    (&tg[0][0])[i] = (short)t;
    (&sr[0][0])[i] = (short)s;
    tpos[lvl][t] = (short)k;  // unique within a level (permutation slice)
    spos[lvl][s] = (short)k;
  }
  __syncthreads();

  for (int j = tid; j < C; j += nt) {
    {  // ---- cls ----
      int idx[4] = {0, 0, 0, 0};
      int cnt = 0, x = j, lvl = L - 1;
      for (;;) {
        int fi = -1, fk = -1;
        for (int i = lvl; i >= 0; --i) {
          const short p = tpos[i][x];
          if (p >= 0) { fi = i; fk = p; break; }
        }
        if (fi < 0) break;
        x = sr[fi][fk];
        lvl = fi - 1;
        idx[cnt++] = x;
      }
      uint2 p;
      p.x = (unsigned)cnt | ((unsigned)idx[0] << 4) | ((unsigned)idx[1] << 15);
      p.y = (unsigned)idx[2] | ((unsigned)idx[3] << 11);
      pc_cls[j] = p;
    }
    {  // ---- box (src/tgt swapped) ----
      int idx[4] = {0, 0, 0, 0};
      int cnt = 0, x = j, lvl = L - 1;
      for (;;) {
        int fi = -1, fk = -1;
        for (int i = lvl; i >= 0; --i) {
          const short p = spos[i][x];
          if (p >= 0) { fi = i; fk = p; break; }
        }
        if (fi < 0) break;
        x = tg[fi][fk];
        lvl = fi - 1;
        idx[cnt++] = x;
      }
      uint2 p;
      p.x = (unsigned)cnt | ((unsigned)idx[0] << 4) | ((unsigned)idx[1] << 15);
      p.y = (unsigned)idx[2] | ((unsigned)idx[3] << 11);
      pc_box[j] = p;
    }
  }
}

__device__ __forceinline__ void gload16(const void* g, void* l) {
  __builtin_amdgcn_global_load_lds(
      (const __attribute__((address_space(1))) unsigned int*)g,
      (__attribute__((address_space(3))) unsigned int*)l, 16, 0, 0);
}

__device__ __forceinline__ void add4(float4& s, const float4 a) {
  s.x += a.x; s.y += a.y; s.z += a.z; s.w += a.w;
}

// Non-temporal float4 store: outputs are write-once/never-read — keep them
// out of L2 so the input stream (which gathers depend on) stays resident.
// NOTE: the builtin requires a native clang vector type, not HIP_vector_type.
typedef float f32x4 __attribute__((ext_vector_type(4)));
__device__ __forceinline__ void nt_store4(float4* p, float4 v) {
  f32x4 w;
  w.x = v.x; w.y = v.y; w.z = v.z; w.w = v.w;
  __builtin_nontemporal_store(w, (f32x4*)p);
}

// ---------------------------------------------------------------------------
// Fused apply — one-shot blocks, max TLP (R7 structure, frozen). One 25.6 KB
// chunk per block staged async to a single LDS buffer; chains load during the
// gload flight; ONE barrier; gather/add/nt-store; exit. 6 blocks/CU.
//   blocks [0, BOX_BLOCKS)  : 1 box row   (1600 float4)
//   blocks [BOX_BLOCKS, ..) : 4 cls rows  (1600 float4)
// Extras deepest-first, base last == reference association order (bit-exact).
// ---------------------------------------------------------------------------
__global__ __launch_bounds__(TB) void apply_fused(
    const float* __restrict__ logits, const float4* __restrict__ box,
    const uint2* __restrict__ pc_cls, const uint2* __restrict__ pc_box,
    float* __restrict__ out_cls, float4* __restrict__ out_box) {
  __shared__ float4 smem[C];  // 25.6 KB
  const int tid = threadIdx.x;
  const int wave = tid >> 6, lane = tid & 63;

  const bool is_box = blockIdx.x < (unsigned)BOX_BLOCKS;
  const void* src = is_box
      ? (const void*)(box + (size_t)blockIdx.x * C)
      : (const void*)(logits + (size_t)(blockIdx.x - BOX_BLOCKS) * (4 * C));

  // stage the 25.6 KB chunk: 5 gload16 per thread (25 x 1 KB units)
#pragma unroll
  for (int k = 0; k < 5; ++k) {
    const int u = k * 5 + wave;
    gload16((const char*)src + u * 1024 + lane * 16,
            (char*)&smem[0] + u * 1024);
  }

  if (is_box) {
    // chain loads overlap the gload flight (12.8 KB table, L2-hot)
    uint2 ch[5];
#pragma unroll
    for (int k = 0; k < 5; ++k) ch[k] = pc_box[tid + k * TB];
    asm volatile("s_waitcnt vmcnt(0)" ::: "memory");
    __syncthreads();

    const float4* row = smem;
    float4* orow = out_box + (size_t)blockIdx.x * C;
#pragma unroll
    for (int k = 0; k < 5; ++k) {
      const int col = tid + k * TB;
      const uint2 p = ch[k];
      const int n = p.x & 0xF;
      float4 a = make_float4(0.f, 0.f, 0.f, 0.f);
      if (n > 3) add4(a, row[(p.y >> 11) & 0x7FF]);
      if (n > 2) add4(a, row[p.y & 0x7FF]);
      if (n > 1) add4(a, row[(p.x >> 15) & 0x7FF]);
      if (n > 0) add4(a, row[(p.x >> 4) & 0x7FF]);
      add4(a, row[col]);  // base last = reference order
      nt_store4(orow + col, a);
    }
  } else {
    const int g = blockIdx.x - BOX_BLOCKS;
    const uint4* pc4 = (const uint4*)pc_cls;  // 2 uint4 = 4 chains
    uint4 chA[5], chB[5];
#pragma unroll
    for (int k = 0; k < 5; ++k) {
      const int s4 = tid + k * TB;
      const int c4 = s4 % 400;
      chA[k] = pc4[2 * c4];
      chB[k] = pc4[2 * c4 + 1];
    }
    asm volatile("s_waitcnt vmcnt(0)" ::: "memory");
    __syncthreads();

    const float* rows = (const float*)smem;        // [4][1600]
    float4* o4 = (float4*)out_cls + (size_t)g * C; // [4][400] float4
#pragma unroll
    for (int k = 0; k < 5; ++k) {
      const int s4 = tid + k * TB;  // r*400 + c4
      const int r = s4 / 400;
      const int c4 = s4 - r * 400;
      const float* rw = rows + r * C;
      float4 v = ((const float4*)rw)[c4];
      const uint4 pA = chA[k], pB = chB[k];
      float acc;
      {
        const int n = pA.x & 0xF; acc = 0.f;
        if (n > 3) acc += rw[(pA.y >> 11) & 0x7FF];
        if (n > 2) acc += rw[pA.y & 0x7FF];
        if (n > 1) acc += rw[(pA.x >> 15) & 0x7FF];
        if (n > 0) acc += rw[(pA.x >> 4) & 0x7FF];
        v.x = acc + v.x;
      }
      {
        const int n = pA.z & 0xF; acc = 0.f;
        if (n > 3) acc += rw[(pA.w >> 11) & 0x7FF];
        if (n > 2) acc += rw[pA.w & 0x7FF];
        if (n > 1) acc += rw[(pA.z >> 15) & 0x7FF];
        if (n > 0) acc += rw[(pA.z >> 4) & 0x7FF];
        v.y = acc + v.y;
      }
      {
        const int n = pB.x & 0xF; acc = 0.f;
        if (n > 3) acc += rw[(pB.y >> 11) & 0x7FF];
        if (n > 2) acc += rw[pB.y & 0x7FF];
        if (n > 1) acc += rw[(pB.x >> 15) & 0x7FF];
        if (n > 0) acc += rw[(pB.x >> 4) & 0x7FF];
        v.z = acc + v.z;
      }
      {
        const int n = pB.z & 0xF; acc = 0.f;
        if (n > 3) acc += rw[(pB.w >> 11) & 0x7FF];
        if (n > 2) acc += rw[pB.w & 0x7FF];
        if (n > 1) acc += rw[(pB.z >> 15) & 0x7FF];
        if (n > 0) acc += rw[(pB.z >> 4) & 0x7FF];
        v.w = acc + v.w;
      }
      nt_store4(o4 + s4, v);
    }
  }
}

}  // namespace

extern "C" void kernel_launch(void* const* d_in, const int* in_sizes, int n_in,
                              void* d_out, int out_size, void* d_ws, size_t ws_size,
                              hipStream_t stream) {
  const float* logits = (const float*)d_in[0];  // (N, C)
  const float* boxr   = (const float*)d_in[1];  // (N, 4C) == (N, C) float4
  const int*   tgt    = (const int*)d_in[2];    // (L, K)
  const int*   src    = (const int*)d_in[3];    // (L, K)

  float* out_cls = (float*)d_out;                // (N, C)
  float* out_box = out_cls + (size_t)NROWS * C;  // (N, 4C)

  uint2* pc_cls = (uint2*)d_ws;  // 12.8 KB
  uint2* pc_box = pc_cls + C;    // 12.8 KB

  build_chains<<<1, 1024, 0, stream>>>(tgt, src, pc_cls, pc_box);
  apply_fused<<<BOX_BLOCKS + CLS_BLOCKS, TB, 0, stream>>>(
      logits, (const float4*)boxr, pc_cls, pc_box, out_cls, (float4*)out_box);
}

// Round 10
// 91.216 us; speedup vs baseline: 2.2469x; 1.0022x over previous
//
#include <hip/hip_runtime.h>

namespace {

constexpr int NROWS = 8192;  // N
constexpr int C = 1600;      // classes
constexpr int L = 4;         // hierarchy levels
constexpr int K = 256;       // labels per level

constexpr int TB = 512;                 // 8 waves -> 4 blocks/CU = 32 waves (100%)
constexpr int BOX_BLOCKS = NROWS;       // one box row per block (25.6 KB)
constexpr int CLS_BLOCKS = NROWS / 4;   // one 4-row cls group per block

// Packed extras chain for column j: out[j] = (deepest-first extras) + in[j]
// x = n | idx0<<4 | idx1<<15 ; y = idx2 | idx3<<11   (indices < 2048)

// ---------------------------------------------------------------------------
// Build per-column extras chains (verified walk, unchanged since R3).
// cls : level i writes tgt_i[k] = old[src_i[k]] + orig[tgt_i[k]]
// box : level i writes src_i[k] = old[tgt_i[k]] + orig[src_i[k]]
// ---------------------------------------------------------------------------
__global__ __launch_bounds__(1024) void build_chains(
    const int* __restrict__ tgt, const int* __restrict__ src,
    uint2* __restrict__ pc_cls, uint2* __restrict__ pc_box) {
  __shared__ short tpos[L][C];
  __shared__ short spos[L][C];
  __shared__ short tg[L][K];
  __shared__ short sr[L][K];
  const int tid = threadIdx.x, nt = blockDim.x;

  for (int i = tid; i < L * C; i += nt) {
    (&tpos[0][0])[i] = -1;
    (&spos[0][0])[i] = -1;
  }
  __syncthreads();
  for (int i = tid; i < L * K; i += nt) {
    const int lvl = i / K, k = i % K;
    const int t = tgt[i], s = src[i];
    (&tg[0][0])[i] = (short)t;
    (&sr[0][0])[i] = (short)s;
    tpos[lvl][t] = (short)k;  // unique within a level (permutation slice)
    spos[lvl][s] = (short)k;
  }
  __syncthreads();

  for (int j = tid; j < C; j += nt) {
    {  // ---- cls ----
      int idx[4] = {0, 0, 0, 0};
      int cnt = 0, x = j, lvl = L - 1;
      for (;;) {
        int fi = -1, fk = -1;
        for (int i = lvl; i >= 0; --i) {
          const short p = tpos[i][x];
          if (p >= 0) { fi = i; fk = p; break; }
        }
        if (fi < 0) break;
        x = sr[fi][fk];
        lvl = fi - 1;
        idx[cnt++] = x;
      }
      uint2 p;
      p.x = (unsigned)cnt | ((unsigned)idx[0] << 4) | ((unsigned)idx[1] << 15);
      p.y = (unsigned)idx[2] | ((unsigned)idx[3] << 11);
      pc_cls[j] = p;
    }
    {  // ---- box (src/tgt swapped) ----
      int idx[4] = {0, 0, 0, 0};
      int cnt = 0, x = j, lvl = L - 1;
      for (;;) {
        int fi = -1, fk = -1;
        for (int i = lvl; i >= 0; --i) {
          const short p = spos[i][x];
          if (p >= 0) { fi = i; fk = p; break; }
        }
        if (fi < 0) break;
        x = tg[fi][fk];
        lvl = fi - 1;
        idx[cnt++] = x;
      }
      uint2 p;
      p.x = (unsigned)cnt | ((unsigned)idx[0] << 4) | ((unsigned)idx[1] << 15);
      p.y = (unsigned)idx[2] | ((unsigned)idx[3] << 11);
      pc_box[j] = p;
    }
  }
}

__device__ __forceinline__ void gload16(const void* g, void* l) {
  __builtin_amdgcn_global_load_lds(
      (const __attribute__((address_space(1))) unsigned int*)g,
      (__attribute__((address_space(3))) unsigned int*)l, 16, 0, 0);
}

__device__ __forceinline__ void add4(float4& s, const float4 a) {
  s.x += a.x; s.y += a.y; s.z += a.z; s.w += a.w;
}

// Non-temporal float4 store: outputs are write-once/never-read — keep them
// out of L2/L3 so the input stream (which gathers depend on) stays resident.
// NOTE: the builtin requires a native clang vector type, not HIP_vector_type.
typedef float f32x4 __attribute__((ext_vector_type(4)));
__device__ __forceinline__ void nt_store4(float4* p, float4 v) {
  f32x4 w;
  w.x = v.x; w.y = v.y; w.z = v.z; w.w = v.w;
  __builtin_nontemporal_store(w, (f32x4*)p);
}

// ---------------------------------------------------------------------------
// Fused apply — one-shot blocks, max TLP (R7/R9 structure), now 8 waves/block
// so the CU wave cap (4 blocks x 8 waves = 32) gives 100% theoretical
// occupancy regardless of LDS allocation granularity. One 25.6 KB chunk per
// block staged async; chains load during the gload flight; ONE barrier;
// gather/add/nt-store; exit. All tail predicates are wave-uniform.
//   blocks [0, BOX_BLOCKS)  : 1 box row   (1600 float4)
//   blocks [BOX_BLOCKS, ..) : 4 cls rows  (1600 float4)
// Extras deepest-first, base last == reference association order (bit-exact).
// ---------------------------------------------------------------------------
__global__ __launch_bounds__(TB) void apply_fused(
    const float* __restrict__ logits, const float4* __restrict__ box,
    const uint2* __restrict__ pc_cls, const uint2* __restrict__ pc_box,
    float* __restrict__ out_cls, float4* __restrict__ out_box) {
  __shared__ float4 smem[C];  // 25.6 KB
  const int tid = threadIdx.x;
  const int wave = tid >> 6, lane = tid & 63;

  const bool is_box = blockIdx.x < (unsigned)BOX_BLOCKS;
  const void* src = is_box
      ? (const void*)(box + (size_t)blockIdx.x * C)
      : (const void*)(logits + (size_t)(blockIdx.x - BOX_BLOCKS) * (4 * C));

  // stage the 25.6 KB chunk: 25 x 1 KB units over 8 waves (wave 0 takes 4)
#pragma unroll
  for (int k = 0; k < 4; ++k) {
    const int u = k * 8 + wave;
    if (u < 25)
      gload16((const char*)src + u * 1024 + lane * 16,
              (char*)&smem[0] + u * 1024);
  }

  if (is_box) {
    // chain loads overlap the gload flight (12.8 KB table, L1/L2-hot)
    uint2 ch[4];
#pragma unroll
    for (int k = 0; k < 4; ++k) {
      const int col = tid + k * TB;
      if (col < C) ch[k] = pc_box[col];
    }
    asm volatile("s_waitcnt vmcnt(0)" ::: "memory");
    __syncthreads();

    const float4* row = smem;
    float4* orow = out_box + (size_t)blockIdx.x * C;
#pragma unroll
    for (int k = 0; k < 4; ++k) {
      const int col = tid + k * TB;
      if (col < C) {
        const uint2 p = ch[k];
        const int n = p.x & 0xF;
        float4 a = make_float4(0.f, 0.f, 0.f, 0.f);
        if (n > 3) add4(a, row[(p.y >> 11) & 0x7FF]);
        if (n > 2) add4(a, row[p.y & 0x7FF]);
        if (n > 1) add4(a, row[(p.x >> 15) & 0x7FF]);
        if (n > 0) add4(a, row[(p.x >> 4) & 0x7FF]);
        add4(a, row[col]);  // base last = reference order
        nt_store4(orow + col, a);
      }
    }
  } else {
    const int g = blockIdx.x - BOX_BLOCKS;
    const uint4* pc4 = (const uint4*)pc_cls;  // 2 uint4 = 4 chains
    uint4 chA[4], chB[4];
#pragma unroll
    for (int k = 0; k < 4; ++k) {
      const int s4 = tid + k * TB;
      if (s4 < C) {
        const int c4 = s4 % 400;
        chA[k] = pc4[2 * c4];
        chB[k] = pc4[2 * c4 + 1];
      }
    }
    asm volatile("s_waitcnt vmcnt(0)" ::: "memory");
    __syncthreads();

    const float* rows = (const float*)smem;        // [4][1600]
    float4* o4 = (float4*)out_cls + (size_t)g * C; // [4][400] float4
#pragma unroll
    for (int k = 0; k < 4; ++k) {
      const int s4 = tid + k * TB;  // r*400 + c4
      if (s4 < C) {
        const int r = s4 / 400;
        const int c4 = s4 - r * 400;
        const float* rw = rows + r * C;
        float4 v = ((const float4*)rw)[c4];
        const uint4 pA = chA[k], pB = chB[k];
        float acc;
        {
          const int n = pA.x & 0xF; acc = 0.f;
          if (n > 3) acc += rw[(pA.y >> 11) & 0x7FF];
          if (n > 2) acc += rw[pA.y & 0x7FF];
          if (n > 1) acc += rw[(pA.x >> 15) & 0x7FF];
          if (n > 0) acc += rw[(pA.x >> 4) & 0x7FF];
          v.x = acc + v.x;
        }
        {
          const int n = pA.z & 0xF; acc = 0.f;
          if (n > 3) acc += rw[(pA.w >> 11) & 0x7FF];
          if (n > 2) acc += rw[pA.w & 0x7FF];
          if (n > 1) acc += rw[(pA.z >> 15) & 0x7FF];
          if (n > 0) acc += rw[(pA.z >> 4) & 0x7FF];
          v.y = acc + v.y;
        }
        {
          const int n = pB.x & 0xF; acc = 0.f;
          if (n > 3) acc += rw[(pB.y >> 11) & 0x7FF];
          if (n > 2) acc += rw[pB.y & 0x7FF];
          if (n > 1) acc += rw[(pB.x >> 15) & 0x7FF];
          if (n > 0) acc += rw[(pB.x >> 4) & 0x7FF];
          v.z = acc + v.z;
        }
        {
          const int n = pB.z & 0xF; acc = 0.f;
          if (n > 3) acc += rw[(pB.w >> 11) & 0x7FF];
          if (n > 2) acc += rw[pB.w & 0x7FF];
          if (n > 1) acc += rw[(pB.z >> 15) & 0x7FF];
          if (n > 0) acc += rw[(pB.z >> 4) & 0x7FF];
          v.w = acc + v.w;
        }
        nt_store4(o4 + s4, v);
      }
    }
  }
}

}  // namespace

extern "C" void kernel_launch(void* const* d_in, const int* in_sizes, int n_in,
                              void* d_out, int out_size, void* d_ws, size_t ws_size,
                              hipStream_t stream) {
  const float* logits = (const float*)d_in[0];  // (N, C)
  const float* boxr   = (const float*)d_in[1];  // (N, 4C) == (N, C) float4
  const int*   tgt    = (const int*)d_in[2];    // (L, K)
  const int*   src    = (const int*)d_in[3];    // (L, K)

  float* out_cls = (float*)d_out;                // (N, C)
  float* out_box = out_cls + (size_t)NROWS * C;  // (N, 4C)

  uint2* pc_cls = (uint2*)d_ws;  // 12.8 KB
  uint2* pc_box = pc_cls + C;    // 12.8 KB

  build_chains<<<1, 1024, 0, stream>>>(tgt, src, pc_cls, pc_box);
  apply_fused<<<BOX_BLOCKS + CLS_BLOCKS, TB, 0, stream>>>(
      logits, (const float4*)boxr, pc_cls, pc_box, out_cls, (float4*)out_box);
}